// Round 8
// baseline (65.077 us; speedup 1.0000x reference)
//
#include <hip/hip_runtime.h>
#include <math.h>

namespace {

constexpr int C      = 25;
constexpr int ROWS   = 256;          // rows per tile (= blockDim.x)
constexpr int TILE_F = ROWS * C;     // 6400 floats = 25.6 KB
constexpr int NBLK   = 768;          // 3 blocks/CU (LDS: 3x51.9KB < 160KB)

typedef const __attribute__((address_space(1))) void* gp_t;
typedef __attribute__((address_space(3))) void* lp_t;

__device__ __forceinline__ void load16_lds(const float* g, float* l) {
  // 16B per lane, LDS dest = wave-uniform base + lane*16 (lane-linear idiom)
  __builtin_amdgcn_global_load_lds((gp_t)g, (lp_t)l, 16, 0, 0);
}

// ws layout: double ce_part[NBLK]; int ln_part[NBLK]; unsigned counter
__global__ __launch_bounds__(256)
void k_ce(const float* __restrict__ x, const int* __restrict__ labels,
          const float* __restrict__ M, int B,
          double* __restrict__ ce_part, int* __restrict__ ln_part,
          unsigned* __restrict__ counter, float* __restrict__ out) {
  __shared__ float tile[2][TILE_F];  // 51.2 KB double buffer
  __shared__ float wsum[4];
  __shared__ int   wmax[4];
  // finalize scratch (small)
  __shared__ float  colsq[C];
  __shared__ double sred[4];
  __shared__ int    ired[4];
  __shared__ double tred[4];
  __shared__ int    s_last;
  __shared__ int    s_amlast;

  const int t      = threadIdx.x;
  const int bid    = blockIdx.x;
  const int ntiles = B / ROWS;

  // bijective contiguous chunking: first r blocks get q+1 tiles, rest q
  const int q = ntiles / NBLK, r = ntiles % NBLK;
  const int ti0 = (bid < r) ? bid * (q + 1) : r * (q + 1) + (bid - r) * q;
  const int ti1 = ti0 + ((bid < r) ? (q + 1) : q);

  float ce_local = 0.f;
  int   best     = -1;
  int   cur      = 0;

  // ---- prologue: stage first tile, prefetch its labels
  int lab = 0;
  if (ti0 < ti1) {
    const float* g = x + (size_t)ti0 * TILE_F;
#pragma unroll
    for (int k = 0; k < 6; ++k)
      load16_lds(g + (k * 256 + t) * 4, &tile[0][(k * 256 + t) * 4]);
    if (t < 64) load16_lds(g + (1536 + t) * 4, &tile[0][(1536 + t) * 4]);
    lab = labels[(size_t)ti0 * ROWS + t];
  }

  for (int ti = ti0; ti < ti1; ++ti) {
    __syncthreads();  // drains vmcnt(0): tile[cur] staged & visible block-wide

    const int tnext = ti + 1;
    int labn = 0;
    if (tnext < ti1) {
      const float* g = x + (size_t)tnext * TILE_F;
      float* buf = tile[cur ^ 1];
#pragma unroll
      for (int k = 0; k < 6; ++k)
        load16_lds(g + (k * 256 + t) * 4, &buf[(k * 256 + t) * 4]);
      if (t < 64) load16_lds(g + (1536 + t) * 4, &buf[(1536 + t) * 4]);
      labn = labels[(size_t)tnext * ROWS + t];  // prefetch under compute
    }

    // ---- compute row t of tile[cur]; stride-25-dword LDS reads (2-way = free)
    const float* rr = &tile[cur][t * C];
    float e[C];
#pragma unroll
    for (int c = 0; c < C; ++c) e[c] = rr[c];

    float m = e[0];
#pragma unroll
    for (int c = 1; c < C; ++c) m = fmaxf(m, e[c]);
    float s = 0.f, xl = 0.f;
#pragma unroll
    for (int c = 0; c < C; ++c) {
      s += __expf(e[c] - m);
      xl = (c == lab) ? e[c] : xl;  // static-index in-register select
    }
    ce_local += (m + __logf(s)) - xl;

    // pairs are (even t, t+1): never straddle a wave
    const int nxt = __shfl_down(lab, 1, 64);
    if (((t & 1) == 0) && lab != nxt) best = ((ti * ROWS) + t) >> 1;

    lab = labn;
    cur ^= 1;
  }

  // ---- deterministic per-block partials
#pragma unroll
  for (int off = 32; off; off >>= 1) {
    ce_local += __shfl_down(ce_local, off, 64);
    best = max(best, __shfl_down(best, off, 64));
  }
  const int lane = t & 63, wid = t >> 6;
  if (lane == 0) { wsum[wid] = ce_local; wmax[wid] = best; }
  __syncthreads();
  if (t == 0) {
    ce_part[bid] = (double)((wsum[0] + wsum[1]) + (wsum[2] + wsum[3]));
    ln_part[bid] = max(max(wmax[0], wmax[1]), max(wmax[2], wmax[3]));
    __threadfence();                       // release partials device-wide
    unsigned old = atomicAdd(counter, 1u); // device-scope
    s_amlast = (old == (unsigned)(NBLK - 1));
  }
  __syncthreads();
  if (!s_amlast) return;
  __threadfence();  // acquire: order partial reads after counter observation

  // ---- finalize (last-finishing block only) ----
  if (t < C) {
    float s = 0.f;
    for (int r2 = 0; r2 < C; ++r2) {
      float mm = M[r2 * C + t];
      s += mm * mm;
    }
    colsq[t] = s;
  }

  double ce = 0.0;
  int ln = -1;
  for (int i = t; i < NBLK; i += 256) {
    ce += ce_part[i];
    ln = max(ln, ln_part[i]);
  }
#pragma unroll
  for (int off = 32; off; off >>= 1) {
    ce += __shfl_down(ce, off, 64);
    ln = max(ln, __shfl_down(ln, off, 64));
  }
  if (lane == 0) { sred[wid] = ce; ired[wid] = ln; }
  __syncthreads();
  if (t == 0) s_last = max(max(ired[0], ired[1]), max(ired[2], ired[3]));
  __syncthreads();
  const int last_neg = s_last;
  const int P = B / 2;

  double tail = 0.0;  // suffix past last_neg is all same-label by construction
  for (int p = last_neg + 1 + t; p < P; p += 256) {
    const float* e2 = x + (size_t)p * (2 * C);
    float s = 0.f;
#pragma unroll
    for (int c = 0; c < C; ++c) {
      float d = e2[c] - e2[C + c];
      s = fmaf(d * d, colsq[c], s);
    }
    tail += (double)sqrtf(s);
  }
  float norm_last = 0.f;
  if (t == 0 && last_neg >= 0) {
    const float* e2 = x + (size_t)last_neg * (2 * C);
    float s = 0.f;
#pragma unroll
    for (int c = 0; c < C; ++c) {
      float d = e2[c] - e2[C + c];
      s = fmaf(d * d, colsq[c], s);
    }
    norm_last = sqrtf(s);
  }
#pragma unroll
  for (int off = 32; off; off >>= 1) tail += __shfl_down(tail, off, 64);
  if (lane == 0) tred[wid] = tail;
  __syncthreads();
  if (t == 0) {
    double tl    = (tred[0] + tred[1]) + (tred[2] + tred[3]);
    double cesum = (sred[0] + sred[1]) + (sred[2] + sred[3]);
    double cem   = cesum / (double)B;
    float  ml    = fmaxf(1.0f + (float)tl - norm_last, 0.0f);
    out[0] = (float)(cem + 0.005 * (double)ml);
  }
}

}  // namespace

extern "C" void kernel_launch(void* const* d_in, const int* in_sizes, int n_in,
                              void* d_out, int out_size, void* d_ws,
                              size_t ws_size, hipStream_t stream) {
  const float* x      = (const float*)d_in[0];
  const int*   labels = (const int*)d_in[1];
  const float* M      = (const float*)d_in[2];
  float*       out    = (float*)d_out;

  double*   ce_part = (double*)d_ws;
  int*      ln_part = (int*)((char*)d_ws + NBLK * sizeof(double));
  unsigned* counter = (unsigned*)((char*)d_ws + NBLK * (sizeof(double) + sizeof(int)));

  const int B = in_sizes[1];

  hipMemsetAsync(counter, 0, sizeof(unsigned), stream);
  k_ce<<<NBLK, 256, 0, stream>>>(x, labels, M, B, ce_part, ln_part, counter, out);
}

// Round 9
// 54.471 us; speedup vs baseline: 1.1947x; 1.1947x over previous
//
#include <hip/hip_runtime.h>
#include <math.h>

namespace {

constexpr int C      = 25;
constexpr int ROWS   = 256;          // rows per tile (= blockDim.x)
constexpr int TILE_F = ROWS * C;     // 6400 floats = 25.6 KB
constexpr int NBLK   = 512;          // 8192 tiles / 512 = exactly 16 per block

typedef const __attribute__((address_space(1))) void* gp_t;
typedef __attribute__((address_space(3))) void* lp_t;

__device__ __forceinline__ void load16_lds(const float* g, float* l) {
  // 16B per lane, LDS dest = wave-uniform base + lane*16 (lane-linear idiom)
  __builtin_amdgcn_global_load_lds((gp_t)g, (lp_t)l, 16, 0, 0);
}

// ws layout: double ce_part[NBLK]; int ln_part[NBLK]; unsigned counter
__global__ __launch_bounds__(256)
void k_ce(const float* __restrict__ x, const int* __restrict__ labels,
          const float* __restrict__ M, int B,
          double* __restrict__ ce_part, int* __restrict__ ln_part,
          unsigned* __restrict__ counter, float* __restrict__ out) {
  __shared__ float tile[2][TILE_F];  // 51.2 KB double buffer
  __shared__ float wsum[4];
  __shared__ int   wmax[4];
  // finalize scratch (small)
  __shared__ float  colsq[C];
  __shared__ double sred[4];
  __shared__ int    ired[4];
  __shared__ double tred[4];
  __shared__ int    s_last;
  __shared__ int    s_amlast;

  const int t      = threadIdx.x;
  const int bid    = blockIdx.x;
  const int ntiles = B / ROWS;
  const int tpb    = ntiles / NBLK;            // 16 (exact for this problem)
  const int ti0    = bid * tpb;
  const int ti1    = min(ti0 + tpb, ntiles);

  float ce_local = 0.f;
  int   best     = -1;
  int   cur      = 0;

  // ---- prologue: stage first tile, prefetch its labels
  int lab = 0;
  if (ti0 < ti1) {
    const float* g = x + (size_t)ti0 * TILE_F;
#pragma unroll
    for (int k = 0; k < 6; ++k)
      load16_lds(g + (k * 256 + t) * 4, &tile[0][(k * 256 + t) * 4]);
    if (t < 64) load16_lds(g + (1536 + t) * 4, &tile[0][(1536 + t) * 4]);
    lab = labels[(size_t)ti0 * ROWS + t];
  }

  for (int ti = ti0; ti < ti1; ++ti) {
    __syncthreads();  // drains vmcnt(0): tile[cur] staged & visible block-wide

    const int tnext = ti + 1;
    int labn = 0;
    if (tnext < ti1) {
      const float* g = x + (size_t)tnext * TILE_F;
      float* buf = tile[cur ^ 1];
#pragma unroll
      for (int k = 0; k < 6; ++k)
        load16_lds(g + (k * 256 + t) * 4, &buf[(k * 256 + t) * 4]);
      if (t < 64) load16_lds(g + (1536 + t) * 4, &buf[(1536 + t) * 4]);
      labn = labels[(size_t)tnext * ROWS + t];  // prefetch under compute
    }

    // ---- compute row t of tile[cur]; stride-25-dword LDS reads (2-way = free)
    const float* rr = &tile[cur][t * C];
    float e[C];
#pragma unroll
    for (int c = 0; c < C; ++c) e[c] = rr[c];

    float m = e[0];
#pragma unroll
    for (int c = 1; c < C; ++c) m = fmaxf(m, e[c]);
    float s = 0.f, xl = 0.f;
#pragma unroll
    for (int c = 0; c < C; ++c) {
      s += __expf(e[c] - m);
      xl = (c == lab) ? e[c] : xl;  // static-index in-register select
    }
    ce_local += (m + __logf(s)) - xl;

    // pairs are (even t, t+1): never straddle a wave
    const int nxt = __shfl_down(lab, 1, 64);
    if (((t & 1) == 0) && lab != nxt) best = ((ti * ROWS) + t) >> 1;

    lab = labn;
    cur ^= 1;
  }

  // ---- deterministic per-block partials
#pragma unroll
  for (int off = 32; off; off >>= 1) {
    ce_local += __shfl_down(ce_local, off, 64);
    best = max(best, __shfl_down(best, off, 64));
  }
  const int lane = t & 63, wid = t >> 6;
  if (lane == 0) { wsum[wid] = ce_local; wmax[wid] = best; }
  __syncthreads();
  if (t == 0) {
    ce_part[bid] = (double)((wsum[0] + wsum[1]) + (wsum[2] + wsum[3]));
    ln_part[bid] = max(max(wmax[0], wmax[1]), max(wmax[2], wmax[3]));
    __threadfence();                       // release partials device-wide
    unsigned old = atomicAdd(counter, 1u); // device-scope
    s_amlast = (old == (unsigned)(NBLK - 1));
  }
  __syncthreads();
  if (!s_amlast) return;
  __threadfence();  // acquire: order partial reads after counter observation

  // ---- finalize (last-finishing block only) ----
  if (t < C) {
    float s = 0.f;
    for (int r2 = 0; r2 < C; ++r2) {
      float mm = M[r2 * C + t];
      s += mm * mm;
    }
    colsq[t] = s;
  }

  double ce = 0.0;
  int ln = -1;
  for (int i = t; i < NBLK; i += 256) {
    ce += ce_part[i];
    ln = max(ln, ln_part[i]);
  }
#pragma unroll
  for (int off = 32; off; off >>= 1) {
    ce += __shfl_down(ce, off, 64);
    ln = max(ln, __shfl_down(ln, off, 64));
  }
  if (lane == 0) { sred[wid] = ce; ired[wid] = ln; }
  __syncthreads();
  if (t == 0) s_last = max(max(ired[0], ired[1]), max(ired[2], ired[3]));
  __syncthreads();
  const int last_neg = s_last;
  const int P = B / 2;

  double tail = 0.0;  // suffix past last_neg is all same-label by construction
  for (int p = last_neg + 1 + t; p < P; p += 256) {
    const float* e2 = x + (size_t)p * (2 * C);
    float s = 0.f;
#pragma unroll
    for (int c = 0; c < C; ++c) {
      float d = e2[c] - e2[C + c];
      s = fmaf(d * d, colsq[c], s);
    }
    tail += (double)sqrtf(s);
  }
  float norm_last = 0.f;
  if (t == 0 && last_neg >= 0) {
    const float* e2 = x + (size_t)last_neg * (2 * C);
    float s = 0.f;
#pragma unroll
    for (int c = 0; c < C; ++c) {
      float d = e2[c] - e2[C + c];
      s = fmaf(d * d, colsq[c], s);
    }
    norm_last = sqrtf(s);
  }
#pragma unroll
  for (int off = 32; off; off >>= 1) tail += __shfl_down(tail, off, 64);
  if (lane == 0) tred[wid] = tail;
  __syncthreads();
  if (t == 0) {
    double tl    = (tred[0] + tred[1]) + (tred[2] + tred[3]);
    double cesum = (sred[0] + sred[1]) + (sred[2] + sred[3]);
    double cem   = cesum / (double)B;
    float  ml    = fmaxf(1.0f + (float)tl - norm_last, 0.0f);
    out[0] = (float)(cem + 0.005 * (double)ml);
  }
}

}  // namespace

extern "C" void kernel_launch(void* const* d_in, const int* in_sizes, int n_in,
                              void* d_out, int out_size, void* d_ws,
                              size_t ws_size, hipStream_t stream) {
  const float* x      = (const float*)d_in[0];
  const int*   labels = (const int*)d_in[1];
  const float* M      = (const float*)d_in[2];
  float*       out    = (float*)d_out;

  double*   ce_part = (double*)d_ws;
  int*      ln_part = (int*)((char*)d_ws + NBLK * sizeof(double));
  unsigned* counter = (unsigned*)((char*)d_ws + NBLK * (sizeof(double) + sizeof(int)));

  const int B = in_sizes[1];

  hipMemsetAsync(counter, 0, sizeof(unsigned), stream);
  k_ce<<<NBLK, 256, 0, stream>>>(x, labels, M, B, ce_part, ln_part, counter, out);
}

// Round 10
// 41.789 us; speedup vs baseline: 1.5573x; 1.3035x over previous
//
#include <hip/hip_runtime.h>
#include <math.h>

namespace {

constexpr int C      = 25;
constexpr int ROWS   = 256;           // rows per tile (= blockDim.x)
constexpr int TILE_F = ROWS * C;      // 6400 floats = 25.6 KB
constexpr int NBUF   = 3;             // triple buffer -> depth-2 pipeline
constexpr int NBLK   = 512;           // 8192 tiles / 512 = exactly 16 per block

typedef const __attribute__((address_space(1))) void* gp_t;
typedef __attribute__((address_space(3))) void* lp_t;

__device__ __forceinline__ void load16_lds(const float* g, float* l) {
  // 16B/lane; LDS dest = wave-uniform base + lane*16 (lane-linear idiom)
  __builtin_amdgcn_global_load_lds((gp_t)g, (lp_t)l, 16, 0, 0);
}

// Barrier-free k_ce: each wave stages ITS OWN 64-row quarter of each tile and
// computes only rows it staged -> zero inter-wave dependencies in the loop.
// Triple-buffered, counted vmcnt (exactly 8 vmem instructions per wave/tile).
__global__ __launch_bounds__(256)
void k_ce(const float* __restrict__ x, const int* __restrict__ labels, int B,
          double* __restrict__ ce_part, int* __restrict__ ln_part) {
  __shared__ float tile[NBUF][TILE_F];   // 76.8 KB
  __shared__ int   labt[NBUF][ROWS];     // 3 KB (labels staged via LDS too)
  __shared__ float wsum[4];
  __shared__ int   wmax[4];

  const int t      = threadIdx.x;
  const int lane   = t & 63;
  const int w      = t >> 6;            // wave id: owns rows [w*64, w*64+64)
  const int ntiles = B / ROWS;
  const int tpb    = ntiles / NBLK;     // 16 (exact for this problem)
  const int ti0    = blockIdx.x * tpb;
  const int ti1    = ti0 + tpb;

  float ce_local = 0.f;
  int   best     = -1;

  // ---- per-wave stage of its quarter: EXACTLY 8 vmem instr per wave ----
  auto stage = [&](int ti, int b) {
    const float* gq = x + (size_t)ti * TILE_F + w * 1600;  // wave quarter
    float*       lq = &tile[b][w * 1600];
#pragma unroll
    for (int k = 0; k < 6; ++k)  // 6 full-wave b128 (384 float4)
      load16_lds(gq + (k * 64 + lane) * 4, lq + (k * 64 + lane) * 4);
    if (lane < 16) {             // rows tail: 16 float4  (instr 7)
      load16_lds(gq + (384 + lane) * 4, lq + (384 + lane) * 4);
      // labels quarter: 64 ints = 16 x 16B  (instr 8)
      load16_lds((const float*)(labels + (size_t)ti * ROWS + w * 64 + lane * 4),
                 (float*)&labt[b][w * 64 + lane * 4]);
    }
  };

  auto compute = [&](int ti, int b) {
    const float* r = &tile[b][t * C];   // own wave's quarter only
    float e[C];
#pragma unroll
    for (int c = 0; c < C; ++c) e[c] = r[c];
    const int lab = labt[b][t];

    float m = e[0];
#pragma unroll
    for (int c = 1; c < C; ++c) m = fmaxf(m, e[c]);
    float s = 0.f, xl = 0.f;
#pragma unroll
    for (int c = 0; c < C; ++c) {
      s += __expf(e[c] - m);
      xl = (c == lab) ? e[c] : xl;      // static-index in-register select
    }
    ce_local += (m + __logf(s)) - xl;

    // pairs (even t, t+1) are within one wave
    const int nxt = __shfl_down(lab, 1, 64);
    if (((t & 1) == 0) && lab != nxt) best = ((ti * ROWS) + t) >> 1;
  };

  // ---- prologue: 2 tiles in flight (16 vmem instr outstanding per wave)
  if (ti0 < ti1)     stage(ti0,     0);
  if (ti0 + 1 < ti1) stage(ti0 + 1, 1);

  int b = 0;
  for (int ti = ti0; ti < ti1 - 1; ++ti) {
    // drain own wave's loads for tile ti; keep ti+1 (and soon ti+2) in flight
    asm volatile("s_waitcnt vmcnt(8)" ::: "memory");
    if (ti + 2 < ti1) stage(ti + 2, (b + 2) % NBUF);  // overwrites buf(ti-1): safe, program order
    compute(ti, b);
    b = (b + 1) % NBUF;
  }
  asm volatile("s_waitcnt vmcnt(0)" ::: "memory");
  compute(ti1 - 1, b);

  // ---- deterministic per-block partials (only sync point)
#pragma unroll
  for (int off = 32; off; off >>= 1) {
    ce_local += __shfl_down(ce_local, off, 64);
    best = max(best, __shfl_down(best, off, 64));
  }
  if (lane == 0) { wsum[w] = ce_local; wmax[w] = best; }
  __syncthreads();
  if (t == 0) {
    ce_part[blockIdx.x] = (double)((wsum[0] + wsum[1]) + (wsum[2] + wsum[3]));
    ln_part[blockIdx.x] = max(max(wmax[0], wmax[1]), max(wmax[2], wmax[3]));
  }
}

// Finalize: reduce partials; metric tail (suffix past last_neg is all
// same-label by construction) + norm at last_neg; combine. One block.
__global__ __launch_bounds__(256)
void k_fin(const float* __restrict__ x, const float* __restrict__ M,
           const double* __restrict__ ce_part, const int* __restrict__ ln_part,
           int P, int B, float* __restrict__ out) {
  __shared__ float  colsq[C];
  __shared__ double sred[4];
  __shared__ int    ired[4];
  __shared__ double tred[4];
  __shared__ int    s_last;

  const int t = threadIdx.x, lane = t & 63, wid = t >> 6;

  if (t < C) {
    float s = 0.f;
    for (int r = 0; r < C; ++r) {
      float m = M[r * C + t];
      s += m * m;
    }
    colsq[t] = s;
  }

  double ce = 0.0;
  int ln = -1;
  for (int i = t; i < NBLK; i += 256) {
    ce += ce_part[i];
    ln = max(ln, ln_part[i]);
  }
#pragma unroll
  for (int off = 32; off; off >>= 1) {
    ce += __shfl_down(ce, off, 64);
    ln = max(ln, __shfl_down(ln, off, 64));
  }
  if (lane == 0) { sred[wid] = ce; ired[wid] = ln; }
  __syncthreads();
  if (t == 0) s_last = max(max(ired[0], ired[1]), max(ired[2], ired[3]));
  __syncthreads();
  const int last_neg = s_last;

  double tail = 0.0;
  for (int p = last_neg + 1 + t; p < P; p += 256) {
    const float* e = x + (size_t)p * (2 * C);
    float s = 0.f;
#pragma unroll
    for (int c = 0; c < C; ++c) {
      float d = e[c] - e[C + c];
      s = fmaf(d * d, colsq[c], s);
    }
    tail += (double)sqrtf(s);
  }
  float norm_last = 0.f;
  if (t == 0 && last_neg >= 0) {
    const float* e = x + (size_t)last_neg * (2 * C);
    float s = 0.f;
#pragma unroll
    for (int c = 0; c < C; ++c) {
      float d = e[c] - e[C + c];
      s = fmaf(d * d, colsq[c], s);
    }
    norm_last = sqrtf(s);
  }
#pragma unroll
  for (int off = 32; off; off >>= 1) tail += __shfl_down(tail, off, 64);
  if (lane == 0) tred[wid] = tail;
  __syncthreads();
  if (t == 0) {
    double tl    = (tred[0] + tred[1]) + (tred[2] + tred[3]);
    double cesum = (sred[0] + sred[1]) + (sred[2] + sred[3]);
    double cem   = cesum / (double)B;
    float  ml    = fmaxf(1.0f + (float)tl - norm_last, 0.0f);
    out[0] = (float)(cem + 0.005 * (double)ml);
  }
}

}  // namespace

extern "C" void kernel_launch(void* const* d_in, const int* in_sizes, int n_in,
                              void* d_out, int out_size, void* d_ws,
                              size_t ws_size, hipStream_t stream) {
  const float* x      = (const float*)d_in[0];
  const int*   labels = (const int*)d_in[1];
  const float* M      = (const float*)d_in[2];
  float*       out    = (float*)d_out;

  double* ce_part = (double*)d_ws;
  int*    ln_part = (int*)((char*)d_ws + NBLK * sizeof(double));

  const int B = in_sizes[1];
  const int P = B / 2;

  k_ce<<<NBLK, 256, 0, stream>>>(x, labels, B, ce_part, ln_part);
  k_fin<<<1, 256, 0, stream>>>(x, M, ce_part, ln_part, P, B, out);
}

// Round 11
// 39.809 us; speedup vs baseline: 1.6347x; 1.0497x over previous
//
#include <hip/hip_runtime.h>
#include <math.h>

namespace {

constexpr int C      = 25;
constexpr int ROWS   = 256;          // rows per tile (= blockDim.x)
constexpr int TILE_F = ROWS * C;     // 6400 floats = 25.6 KB
constexpr int NBLK   = 512;          // 8192 tiles / 512 = exactly 16 per block

typedef const __attribute__((address_space(1))) void* gp_t;
typedef __attribute__((address_space(3))) void* lp_t;

__device__ __forceinline__ void load16_lds(const float* g, float* l) {
  // 16B per lane, LDS dest = wave-uniform base + lane*16 (lane-linear idiom)
  // aux=2 -> NT (non-temporal/streaming) cache policy: x is read exactly once
  __builtin_amdgcn_global_load_lds((gp_t)g, (lp_t)l, 16, 0, 2);
}

// Fused CE + last_neg pass. Double-buffered async LDS staging; each block
// owns a CONTIGUOUS chunk of tiles (sequential HBM stream).
__global__ __launch_bounds__(256)
void k_ce(const float* __restrict__ x, const int* __restrict__ labels, int B,
          double* __restrict__ ce_part, int* __restrict__ ln_part) {
  __shared__ float tile[2][TILE_F];  // 51.2 KB double buffer
  __shared__ float wsum[4];
  __shared__ int   wmax[4];

  const int t      = threadIdx.x;
  const int ntiles = B / ROWS;
  const int tpb    = ntiles / NBLK;            // 16 (exact for this problem)
  const int ti0    = blockIdx.x * tpb;
  const int ti1    = min(ti0 + tpb, ntiles);

  float ce_local = 0.f;
  int   best     = -1;
  int   cur      = 0;

  // ---- prologue: stage first tile, prefetch its labels
  int lab = 0;
  if (ti0 < ti1) {
    const float* g = x + (size_t)ti0 * TILE_F;
#pragma unroll
    for (int k = 0; k < 6; ++k)
      load16_lds(g + (k * 256 + t) * 4, &tile[0][(k * 256 + t) * 4]);
    if (t < 64) load16_lds(g + (1536 + t) * 4, &tile[0][(1536 + t) * 4]);
    lab = labels[(size_t)ti0 * ROWS + t];
  }

  for (int ti = ti0; ti < ti1; ++ti) {
    __syncthreads();  // drains vmcnt(0): tile[cur] staged & visible block-wide

    const int tnext = ti + 1;
    int labn = 0;
    if (tnext < ti1) {
      const float* g = x + (size_t)tnext * TILE_F;
      float* buf = tile[cur ^ 1];
#pragma unroll
      for (int k = 0; k < 6; ++k)
        load16_lds(g + (k * 256 + t) * 4, &buf[(k * 256 + t) * 4]);
      if (t < 64) load16_lds(g + (1536 + t) * 4, &buf[(1536 + t) * 4]);
      labn = labels[(size_t)tnext * ROWS + t];  // prefetch under compute
    }

    // ---- compute row t of tile[cur]; stride-25-dword LDS reads (2-way = free)
    const float* r = &tile[cur][t * C];
    float e[C];
#pragma unroll
    for (int c = 0; c < C; ++c) e[c] = r[c];

    float m = e[0];
#pragma unroll
    for (int c = 1; c < C; ++c) m = fmaxf(m, e[c]);
    float s = 0.f, xl = 0.f;
#pragma unroll
    for (int c = 0; c < C; ++c) {
      s += __expf(e[c] - m);
      xl = (c == lab) ? e[c] : xl;  // static-index in-register select
    }
    ce_local += (m + __logf(s)) - xl;

    // pairs are (even t, t+1): never straddle a wave
    const int nxt = __shfl_down(lab, 1, 64);
    if (((t & 1) == 0) && lab != nxt) best = ((ti * ROWS) + t) >> 1;

    lab = labn;
    cur ^= 1;
  }

  // ---- deterministic per-block partials
#pragma unroll
  for (int off = 32; off; off >>= 1) {
    ce_local += __shfl_down(ce_local, off, 64);
    best = max(best, __shfl_down(best, off, 64));
  }
  const int lane = t & 63, wid = t >> 6;
  if (lane == 0) { wsum[wid] = ce_local; wmax[wid] = best; }
  __syncthreads();
  if (t == 0) {
    ce_part[blockIdx.x] = (double)((wsum[0] + wsum[1]) + (wsum[2] + wsum[3]));
    ln_part[blockIdx.x] = max(max(wmax[0], wmax[1]), max(wmax[2], wmax[3]));
  }
}

// Finalize: reduce partials; metric tail (suffix past last_neg is all
// same-label by construction) + norm at last_neg; combine. One block.
__global__ __launch_bounds__(256)
void k_fin(const float* __restrict__ x, const float* __restrict__ M,
           const double* __restrict__ ce_part, const int* __restrict__ ln_part,
           int P, int B, float* __restrict__ out) {
  __shared__ float  colsq[C];
  __shared__ double sred[4];
  __shared__ int    ired[4];
  __shared__ double tred[4];
  __shared__ int    s_last;

  const int t = threadIdx.x, lane = t & 63, wid = t >> 6;

  if (t < C) {
    float s = 0.f;
    for (int r = 0; r < C; ++r) {
      float m = M[r * C + t];
      s += m * m;
    }
    colsq[t] = s;
  }

  double ce = 0.0;
  int ln = -1;
  for (int i = t; i < NBLK; i += 256) {
    ce += ce_part[i];
    ln = max(ln, ln_part[i]);
  }
#pragma unroll
  for (int off = 32; off; off >>= 1) {
    ce += __shfl_down(ce, off, 64);
    ln = max(ln, __shfl_down(ln, off, 64));
  }
  if (lane == 0) { sred[wid] = ce; ired[wid] = ln; }
  __syncthreads();
  if (t == 0) s_last = max(max(ired[0], ired[1]), max(ired[2], ired[3]));
  __syncthreads();
  const int last_neg = s_last;

  double tail = 0.0;
  for (int p = last_neg + 1 + t; p < P; p += 256) {
    const float* e = x + (size_t)p * (2 * C);
    float s = 0.f;
#pragma unroll
    for (int c = 0; c < C; ++c) {
      float d = e[c] - e[C + c];
      s = fmaf(d * d, colsq[c], s);
    }
    tail += (double)sqrtf(s);
  }
  float norm_last = 0.f;
  if (t == 0 && last_neg >= 0) {
    const float* e = x + (size_t)last_neg * (2 * C);
    float s = 0.f;
#pragma unroll
    for (int c = 0; c < C; ++c) {
      float d = e[c] - e[C + c];
      s = fmaf(d * d, colsq[c], s);
    }
    norm_last = sqrtf(s);
  }
#pragma unroll
  for (int off = 32; off; off >>= 1) tail += __shfl_down(tail, off, 64);
  if (lane == 0) tred[wid] = tail;
  __syncthreads();
  if (t == 0) {
    double tl    = (tred[0] + tred[1]) + (tred[2] + tred[3]);
    double cesum = (sred[0] + sred[1]) + (sred[2] + sred[3]);
    double cem   = cesum / (double)B;
    float  ml    = fmaxf(1.0f + (float)tl - norm_last, 0.0f);
    out[0] = (float)(cem + 0.005 * (double)ml);
  }
}

}  // namespace

extern "C" void kernel_launch(void* const* d_in, const int* in_sizes, int n_in,
                              void* d_out, int out_size, void* d_ws,
                              size_t ws_size, hipStream_t stream) {
  const float* x      = (const float*)d_in[0];
  const int*   labels = (const int*)d_in[1];
  const float* M      = (const float*)d_in[2];
  float*       out    = (float*)d_out;

  double* ce_part = (double*)d_ws;
  int*    ln_part = (int*)((char*)d_ws + NBLK * sizeof(double));

  const int B = in_sizes[1];
  const int P = B / 2;

  k_ce<<<NBLK, 256, 0, stream>>>(x, labels, B, ce_part, ln_part);
  k_fin<<<1, 256, 0, stream>>>(x, M, ce_part, ln_part, P, B, out);
}